// Round 1
// baseline (3924.533 us; speedup 1.0000x reference)
//
#include <hip/hip_runtime.h>

#define NN 100000   // nodes
#define HH 4        // heads
#define DD 64       // dim per head
#define RR 2        // relations
#define EE 500000   // edges per relation
#define KK 256      // in_feat
#define HD 256      // H*D
#define NEG_SLOPE 0.2f

// order-preserving float->uint encoding for atomicMax
__device__ __forceinline__ unsigned encf(float f){
    unsigned u = __float_as_uint(f);
    return (u & 0x80000000u) ? ~u : (u | 0x80000000u);
}
__device__ __forceinline__ float decf(unsigned e){
    unsigned u = (e & 0x80000000u) ? (e & 0x7fffffffu) : ~e;
    return __uint_as_float(u);
}

// wcat[k][j], j = r*8 + s*4 + h; s=0: W_src·attn_l (el), s=1: W_dst·attn_r (er)
__global__ void k_wcat(const float* __restrict__ Ws, const float* __restrict__ Wd,
                       const float* __restrict__ al, const float* __restrict__ ar,
                       float* __restrict__ wcat){
    int gid = blockIdx.x*blockDim.x + threadIdx.x;
    if (gid >= KK*16) return;
    int k = gid >> 4, j = gid & 15;
    int r = j >> 3, s = (j >> 2) & 1, h = j & 3;
    const float* w = (s ? Wd : Ws) + ((size_t)r*KK + k)*HD + h*DD;
    const float* a = (s ? ar : al) + (size_t)(r*HH + h)*DD;
    float acc = 0.f;
    #pragma unroll 8
    for (int d=0; d<DD; ++d) acc += w[d]*a[d];
    wcat[(k<<4) + j] = acc;
}

// eall[n][j] = x[n,:] @ wcat[:,j]   ([N,16])
__global__ __launch_bounds__(256) void k_eall(const float* __restrict__ x,
                                              const float* __restrict__ wcat,
                                              float* __restrict__ eall){
    int gid = blockIdx.x*blockDim.x + threadIdx.x;
    if (gid >= NN*16) return;
    int n = gid >> 4, j = gid & 15;
    const float* xr = x + (size_t)n*KK;
    float acc = 0.f;
    for (int k = 0; k < KK; k += 4){
        float4 xv = *(const float4*)(xr + k);
        acc += xv.x*wcat[(k+0)*16+j] + xv.y*wcat[(k+1)*16+j]
             + xv.z*wcat[(k+2)*16+j] + xv.w*wcat[(k+3)*16+j];
    }
    eall[gid] = acc;
}

// out = bias0+bias1 broadcast; zero mEnc/denom (both relations)
__global__ void k_init(const float* __restrict__ bias, float* __restrict__ out,
                       unsigned* __restrict__ mEnc, float* __restrict__ denom){
    int gid = blockIdx.x*blockDim.x + threadIdx.x;
    if (gid < NN*HD){
        int f = gid & (HD-1);
        out[gid] = bias[f] + bias[HD + f];
    }
    if (gid < RR*NN*HH){
        mEnc[gid] = 0u;     // below enc(-inf)=0x007FFFFF, safe floor
        denom[gid] = 0.f;
    }
}

// f32 tiled GEMM: C[M,256] = A[M,256] @ B[256,256]
#define TM 64
#define TN 64
#define TK 16
__global__ __launch_bounds__(256) void k_gemm(const float* __restrict__ A,
                                              const float* __restrict__ B,
                                              float* __restrict__ C, int M){
    __shared__ float As[TK][TM+4];
    __shared__ float Bs[TK][TN+4];
    int tid = threadIdx.x;
    int m0 = blockIdx.x * TM;
    int n0 = blockIdx.y * TN;
    int ty = tid >> 4, tx = tid & 15;
    int am = tid >> 2;            // 0..63
    int ak = (tid & 3) << 2;      // 0,4,8,12
    int bk = tid >> 4;            // 0..15
    int bn = (tid & 15) << 2;     // 0..60
    float acc[4][4] = {};
    for (int k0 = 0; k0 < KK; k0 += TK){
        float4 a4 = make_float4(0,0,0,0);
        int row = m0 + am;
        if (row < M) a4 = *(const float4*)(A + (size_t)row*KK + k0 + ak);
        As[ak+0][am] = a4.x; As[ak+1][am] = a4.y;
        As[ak+2][am] = a4.z; As[ak+3][am] = a4.w;
        float4 b4 = *(const float4*)(B + (size_t)(k0+bk)*HD + n0 + bn);
        *(float4*)&Bs[bk][bn] = b4;
        __syncthreads();
        #pragma unroll
        for (int k = 0; k < TK; ++k){
            float a0 = As[k][ty*4+0], a1 = As[k][ty*4+1];
            float a2 = As[k][ty*4+2], a3 = As[k][ty*4+3];
            float4 b = *(float4*)&Bs[k][tx*4];
            acc[0][0] += a0*b.x; acc[0][1] += a0*b.y; acc[0][2] += a0*b.z; acc[0][3] += a0*b.w;
            acc[1][0] += a1*b.x; acc[1][1] += a1*b.y; acc[1][2] += a1*b.z; acc[1][3] += a1*b.w;
            acc[2][0] += a2*b.x; acc[2][1] += a2*b.y; acc[2][2] += a2*b.z; acc[2][3] += a2*b.w;
            acc[3][0] += a3*b.x; acc[3][1] += a3*b.y; acc[3][2] += a3*b.z; acc[3][3] += a3*b.w;
        }
        __syncthreads();
    }
    #pragma unroll
    for (int i = 0; i < 4; ++i){
        int row = m0 + ty*4 + i;
        if (row < M){
            float4 v = make_float4(acc[i][0], acc[i][1], acc[i][2], acc[i][3]);
            *(float4*)(C + (size_t)row*HD + n0 + tx*4) = v;
        }
    }
}

// per edge,head: e = leakyrelu(el[src]+er[dst]); segment-max into mEnc[dst]
__global__ void k_edge_max(const int* __restrict__ src, const int* __restrict__ dst,
                           const float* __restrict__ eall, int roff,
                           float* __restrict__ evals, unsigned* __restrict__ mEnc){
    int gid = blockIdx.x*blockDim.x + threadIdx.x;
    if (gid >= EE*HH) return;
    int e = gid >> 2, h = gid & 3;
    int s = src[e], d = dst[e];
    float v = eall[(size_t)s*16 + roff + h] + eall[(size_t)d*16 + roff + 4 + h];
    v = v > 0.f ? v : NEG_SLOPE * v;
    evals[gid] = v;
    atomicMax(mEnc + (size_t)d*HH + h, encf(v));
}

// ee = exp(e - m[dst]); segment-sum into denom[dst]
__global__ void k_edge_sum(const int* __restrict__ dst,
                           float* __restrict__ evals,
                           const unsigned* __restrict__ mEnc,
                           float* __restrict__ denom){
    int gid = blockIdx.x*blockDim.x + threadIdx.x;
    if (gid >= EE*HH) return;
    int e = gid >> 2, h = gid & 3;
    int d = dst[e];
    float m = decf(mEnc[(size_t)d*HH + h]);
    float ee = __expf(evals[gid] - m);
    evals[gid] = ee;
    atomicAdd(denom + (size_t)d*HH + h, ee);
}

// out[dst] += (ee/denom[dst]) * fs[src]   — 64 lanes x float4 per edge
__global__ __launch_bounds__(256) void k_aggregate(const int* __restrict__ src,
                                                   const int* __restrict__ dst,
                                                   const float* __restrict__ evals,
                                                   const float* __restrict__ denom,
                                                   const float* __restrict__ fs,
                                                   float* __restrict__ out){
    int e = blockIdx.x*4 + (threadIdx.x >> 6);
    int lane = threadIdx.x & 63;
    int s = src[e], d = dst[e];
    int h = lane >> 4;
    float alpha = evals[(size_t)e*HH + h] / denom[(size_t)d*HH + h];
    float4 v = *(const float4*)(fs + (size_t)s*HD + lane*4);
    float* o = out + (size_t)d*HD + lane*4;
    atomicAdd(o+0, alpha*v.x);
    atomicAdd(o+1, alpha*v.y);
    atomicAdd(o+2, alpha*v.z);
    atomicAdd(o+3, alpha*v.w);
}

extern "C" void kernel_launch(void* const* d_in, const int* in_sizes, int n_in,
                              void* d_out, int out_size, void* d_ws, size_t ws_size,
                              hipStream_t stream) {
    const float* x     = (const float*)d_in[0];
    const float* W_src = (const float*)d_in[1];
    const float* W_dst = (const float*)d_in[2];
    const float* al    = (const float*)d_in[3];
    const float* ar    = (const float*)d_in[4];
    const float* bias  = (const float*)d_in[5];
    const int*   sidx  = (const int*)d_in[6];
    const int*   didx  = (const int*)d_in[7];
    float* out = (float*)d_out;

    // workspace carve-up (floats)
    float*    fs    = (float*)d_ws;                      // N*HD      = 25.6M
    float*    eall  = fs + (size_t)NN*HD;                // N*16      =  1.6M
    float*    wcat  = eall + (size_t)NN*16;              // 256*16    =  4096
    unsigned* mEnc  = (unsigned*)(wcat + KK*16);         // R*N*H     =  0.8M
    float*    denom = (float*)(mEnc + (size_t)RR*NN*HH); // R*N*H     =  0.8M
    float*    evals = denom + (size_t)RR*NN*HH;          // E*H       =  2.0M

    k_wcat<<<(KK*16 + 255)/256, 256, 0, stream>>>(W_src, W_dst, al, ar, wcat);
    k_eall<<<(NN*16 + 255)/256, 256, 0, stream>>>(x, wcat, eall);
    k_init<<<(NN*HD + 255)/256, 256, 0, stream>>>(bias, out, mEnc, denom);

    for (int r = 0; r < RR; ++r){
        const float* Wr = W_src + (size_t)r*KK*HD;
        k_gemm<<<dim3((NN + TM-1)/TM, HD/TN), 256, 0, stream>>>(x, Wr, fs, NN);
        const int* sr = sidx + (size_t)r*EE;
        const int* dr = didx + (size_t)r*EE;
        unsigned* mr = mEnc + (size_t)r*NN*HH;
        float*    dn = denom + (size_t)r*NN*HH;
        k_edge_max<<<(EE*HH + 255)/256, 256, 0, stream>>>(sr, dr, eall, r*8, evals, mr);
        k_edge_sum<<<(EE*HH + 255)/256, 256, 0, stream>>>(dr, evals, mr, dn);
        k_aggregate<<<EE/4, 256, 0, stream>>>(sr, dr, evals, dn, fs, out);
    }
}

// Round 2
// 1067.115 us; speedup vs baseline: 3.6777x; 3.6777x over previous
//
#include <hip/hip_runtime.h>

#define NN 100000   // nodes
#define HH 4        // heads
#define DD 64       // dim per head
#define RR 2        // relations
#define EE 500000   // edges per relation
#define KK 256      // in_feat
#define HD 256      // H*D
#define NEG_SLOPE 0.2f

// wcat[k][j], j = r*8 + s*4 + h; s=0: W_src·attn_l (el), s=1: W_dst·attn_r (er)
__global__ void k_wcat(const float* __restrict__ Ws, const float* __restrict__ Wd,
                       const float* __restrict__ al, const float* __restrict__ ar,
                       float* __restrict__ wcat){
    int gid = blockIdx.x*blockDim.x + threadIdx.x;
    if (gid >= KK*16) return;
    int k = gid >> 4, j = gid & 15;
    int r = j >> 3, s = (j >> 2) & 1, h = j & 3;
    const float* w = (s ? Wd : Ws) + ((size_t)r*KK + k)*HD + h*DD;
    const float* a = (s ? ar : al) + (size_t)(r*HH + h)*DD;
    float acc = 0.f;
    #pragma unroll 8
    for (int d=0; d<DD; ++d) acc += w[d]*a[d];
    wcat[(k<<4) + j] = acc;
}

// eall[n][j] = x[n,:] @ wcat[:,j]   ([N,16])
__global__ __launch_bounds__(256) void k_eall(const float* __restrict__ x,
                                              const float* __restrict__ wcat,
                                              float* __restrict__ eall){
    int gid = blockIdx.x*blockDim.x + threadIdx.x;
    if (gid >= NN*16) return;
    int n = gid >> 4, j = gid & 15;
    const float* xr = x + (size_t)n*KK;
    float acc = 0.f;
    for (int k = 0; k < KK; k += 4){
        float4 xv = *(const float4*)(xr + k);
        acc += xv.x*wcat[(k+0)*16+j] + xv.y*wcat[(k+1)*16+j]
             + xv.z*wcat[(k+2)*16+j] + xv.w*wcat[(k+3)*16+j];
    }
    eall[gid] = acc;
}

// zero histogram + scatter cursors
__global__ void k_setup(unsigned* __restrict__ cnt, unsigned* __restrict__ cur){
    int gid = blockIdx.x*blockDim.x + threadIdx.x;
    if (gid < RR*NN){ cnt[gid] = 0u; cur[gid] = 0u; }
}

// histogram of dst per relation (didx is [R,E] flat; r = gid/EE)
__global__ void k_hist(const int* __restrict__ didx, unsigned* __restrict__ cnt){
    int gid = blockIdx.x*blockDim.x + threadIdx.x;
    if (gid >= RR*EE) return;
    int r = gid / EE;
    atomicAdd(&cnt[(size_t)r*NN + didx[gid]], 1u);
}

// single-block exclusive scan of n elements; rowptr[n] = total
__global__ __launch_bounds__(1024) void k_scan(const unsigned* __restrict__ cnt,
                                               unsigned* __restrict__ rowptr, int n){
    __shared__ unsigned ws[16];
    __shared__ unsigned carry_s;
    int tid = threadIdx.x;
    int lane = tid & 63, wid = tid >> 6;
    if (tid == 0) carry_s = 0u;
    __syncthreads();
    for (int base = 0; base < n; base += 1024){
        unsigned carry = carry_s;
        int i = base + tid;
        unsigned v = (i < n) ? cnt[i] : 0u;
        unsigned x = v;
        #pragma unroll
        for (int off = 1; off < 64; off <<= 1){
            unsigned t = __shfl_up(x, off, 64);
            if (lane >= off) x += t;
        }
        if (lane == 63) ws[wid] = x;
        __syncthreads();
        if (wid == 0){
            unsigned wv = (lane < 16) ? ws[lane] : 0u;
            #pragma unroll
            for (int off = 1; off < 16; off <<= 1){
                unsigned t = __shfl_up(wv, off, 64);
                if (lane >= off) wv += t;
            }
            if (lane < 16) ws[lane] = wv;   // inclusive wave sums
        }
        __syncthreads();
        unsigned wbase = (wid == 0) ? 0u : ws[wid-1];
        if (i < n) rowptr[i] = carry + (x + wbase) - v;  // exclusive
        __syncthreads();
        if (tid == 1023) carry_s = carry + ws[15];       // + chunk total
        __syncthreads();
    }
    if (tid == 0) rowptr[n] = carry_s;
}

// scatter src ids into dst-grouped slots
__global__ void k_scatter(const int* __restrict__ sidx, const int* __restrict__ didx,
                          const unsigned* __restrict__ rowptr, unsigned* __restrict__ cur,
                          int* __restrict__ esrc){
    int gid = blockIdx.x*blockDim.x + threadIdx.x;
    if (gid >= RR*EE) return;
    int r = gid / EE;
    size_t rn = (size_t)r*NN + didx[gid];
    unsigned pos = rowptr[rn] + atomicAdd(&cur[rn], 1u);
    esrc[pos] = sidx[gid];
}

// f32 tiled GEMM: C[M,256] = A[M,256] @ B[256,256]
#define TM 64
#define TN 64
#define TK 16
__global__ __launch_bounds__(256) void k_gemm(const float* __restrict__ A,
                                              const float* __restrict__ B,
                                              float* __restrict__ C, int M){
    __shared__ float As[TK][TM+4];
    __shared__ float Bs[TK][TN+4];
    int tid = threadIdx.x;
    int m0 = blockIdx.x * TM;
    int n0 = blockIdx.y * TN;
    int ty = tid >> 4, tx = tid & 15;
    int am = tid >> 2;
    int ak = (tid & 3) << 2;
    int bk = tid >> 4;
    int bn = (tid & 15) << 2;
    float acc[4][4] = {};
    for (int k0 = 0; k0 < KK; k0 += TK){
        float4 a4 = make_float4(0,0,0,0);
        int row = m0 + am;
        if (row < M) a4 = *(const float4*)(A + (size_t)row*KK + k0 + ak);
        As[ak+0][am] = a4.x; As[ak+1][am] = a4.y;
        As[ak+2][am] = a4.z; As[ak+3][am] = a4.w;
        float4 b4 = *(const float4*)(B + (size_t)(k0+bk)*HD + n0 + bn);
        *(float4*)&Bs[bk][bn] = b4;
        __syncthreads();
        #pragma unroll
        for (int k = 0; k < TK; ++k){
            float a0 = As[k][ty*4+0], a1 = As[k][ty*4+1];
            float a2 = As[k][ty*4+2], a3 = As[k][ty*4+3];
            float4 b = *(float4*)&Bs[k][tx*4];
            acc[0][0] += a0*b.x; acc[0][1] += a0*b.y; acc[0][2] += a0*b.z; acc[0][3] += a0*b.w;
            acc[1][0] += a1*b.x; acc[1][1] += a1*b.y; acc[1][2] += a1*b.z; acc[1][3] += a1*b.w;
            acc[2][0] += a2*b.x; acc[2][1] += a2*b.y; acc[2][2] += a2*b.z; acc[2][3] += a2*b.w;
            acc[3][0] += a3*b.x; acc[3][1] += a3*b.y; acc[3][2] += a3*b.z; acc[3][3] += a3*b.w;
        }
        __syncthreads();
    }
    #pragma unroll
    for (int i = 0; i < 4; ++i){
        int row = m0 + ty*4 + i;
        if (row < M){
            float4 v = make_float4(acc[i][0], acc[i][1], acc[i][2], acc[i][3]);
            *(float4*)(C + (size_t)row*HD + n0 + tx*4) = v;
        }
    }
}

// one wave per dst node: local softmax over its CSR segment + gather-accumulate.
// FIRST: out = acc + bias0+bias1 ; else: out += acc. No atomics anywhere.
template<int FIRST>
__global__ __launch_bounds__(256) void k_agg(const unsigned* __restrict__ rp,
                                             const int* __restrict__ esrc,
                                             const float* __restrict__ eall, int roff,
                                             const float* __restrict__ fs,
                                             const float* __restrict__ bias,
                                             float* __restrict__ out){
    int n = blockIdx.x*4 + (threadIdx.x >> 6);
    int lane = threadIdx.x & 63;
    int h = lane >> 4;
    unsigned beg = rp[n], end = rp[n+1];
    float er = eall[(size_t)n*16 + roff + 4 + h];
    // pass 1: max
    float m = -1e30f;
    for (unsigned u = beg; u < end; ++u){
        int s = esrc[u];
        float v = eall[(size_t)s*16 + roff + h] + er;
        v = v > 0.f ? v : NEG_SLOPE*v;
        m = fmaxf(m, v);
    }
    // pass 2: denom
    float den = 0.f;
    for (unsigned u = beg; u < end; ++u){
        int s = esrc[u];
        float v = eall[(size_t)s*16 + roff + h] + er;
        v = v > 0.f ? v : NEG_SLOPE*v;
        den += __expf(v - m);
    }
    float inv = den > 0.f ? 1.f/den : 0.f;
    // pass 3: weighted gather
    float ax = 0.f, ay = 0.f, az = 0.f, aw = 0.f;
    for (unsigned u = beg; u < end; ++u){
        int s = esrc[u];
        float v = eall[(size_t)s*16 + roff + h] + er;
        v = v > 0.f ? v : NEG_SLOPE*v;
        float a = __expf(v - m) * inv;
        float4 f = *(const float4*)(fs + (size_t)s*HD + lane*4);
        ax += a*f.x; ay += a*f.y; az += a*f.z; aw += a*f.w;
    }
    float* o = out + (size_t)n*HD + lane*4;
    if (FIRST){
        const float4 b0 = *(const float4*)(bias + lane*4);
        const float4 b1 = *(const float4*)(bias + HD + lane*4);
        float4 v = make_float4(ax + b0.x + b1.x, ay + b0.y + b1.y,
                               az + b0.z + b1.z, aw + b0.w + b1.w);
        *(float4*)o = v;
    } else {
        float4 p = *(float4*)o;
        float4 v = make_float4(ax + p.x, ay + p.y, az + p.z, aw + p.w);
        *(float4*)o = v;
    }
}

extern "C" void kernel_launch(void* const* d_in, const int* in_sizes, int n_in,
                              void* d_out, int out_size, void* d_ws, size_t ws_size,
                              hipStream_t stream) {
    const float* x     = (const float*)d_in[0];
    const float* W_src = (const float*)d_in[1];
    const float* W_dst = (const float*)d_in[2];
    const float* al    = (const float*)d_in[3];
    const float* ar    = (const float*)d_in[4];
    const float* bias  = (const float*)d_in[5];
    const int*   sidx  = (const int*)d_in[6];
    const int*   didx  = (const int*)d_in[7];
    float* out = (float*)d_out;

    // workspace carve-up
    float*    fs     = (float*)d_ws;                        // N*HD      = 25.6M f
    float*    eall   = fs + (size_t)NN*HD;                  // N*16      =  1.6M f
    float*    wcat   = eall + (size_t)NN*16;                // 4096 f
    unsigned* cnt    = (unsigned*)(wcat + KK*16);           // R*N
    unsigned* cur    = cnt + (size_t)RR*NN;                 // R*N
    unsigned* rowptr = cur + (size_t)RR*NN;                 // R*N + 8
    int*      esrc   = (int*)(rowptr + (size_t)RR*NN + 8);  // R*E

    k_wcat<<<(KK*16 + 255)/256, 256, 0, stream>>>(W_src, W_dst, al, ar, wcat);
    k_eall<<<(NN*16 + 255)/256, 256, 0, stream>>>(x, wcat, eall);
    k_setup<<<(RR*NN + 255)/256, 256, 0, stream>>>(cnt, cur);
    k_hist<<<(RR*EE + 255)/256, 256, 0, stream>>>(didx, cnt);
    k_scan<<<1, 1024, 0, stream>>>(cnt, rowptr, RR*NN);
    k_scatter<<<(RR*EE + 255)/256, 256, 0, stream>>>(sidx, didx, rowptr, cur, esrc);

    for (int r = 0; r < RR; ++r){
        const float* Wr = W_src + (size_t)r*KK*HD;
        k_gemm<<<dim3((NN + TM-1)/TM, HD/TN), 256, 0, stream>>>(x, Wr, fs, NN);
        const unsigned* rp = rowptr + (size_t)r*NN;
        if (r == 0)
            k_agg<1><<<NN/4, 256, 0, stream>>>(rp, esrc, eall, r*8, fs, bias, out);
        else
            k_agg<0><<<NN/4, 256, 0, stream>>>(rp, esrc, eall, r*8, fs, bias, out);
    }
}

// Round 3
// 560.237 us; speedup vs baseline: 7.0051x; 1.9048x over previous
//
#include <hip/hip_runtime.h>
#include <hip/hip_bf16.h>

#define NN 100000   // nodes
#define HH 4        // heads
#define DD 64       // dim per head
#define RR 2        // relations
#define EE 500000   // edges per relation
#define KK 256      // in_feat
#define HD 256      // H*D
#define NEG_SLOPE 0.2f

typedef __attribute__((ext_vector_type(8))) short bfx8;
typedef __attribute__((ext_vector_type(4))) float f32x4;

__device__ __forceinline__ ushort f2bf(float f){
    __hip_bfloat16 h = __float2bfloat16(f);
    return *(ushort*)&h;
}

// wcat[k][j], j = r*8 + s*4 + h; s=0: W_src·attn_l (el), s=1: W_dst·attn_r (er)
__global__ void k_wcat(const float* __restrict__ Ws, const float* __restrict__ Wd,
                       const float* __restrict__ al, const float* __restrict__ ar,
                       float* __restrict__ wcat){
    int gid = blockIdx.x*blockDim.x + threadIdx.x;
    if (gid >= KK*16) return;
    int k = gid >> 4, j = gid & 15;
    int r = j >> 3, s = (j >> 2) & 1, h = j & 3;
    const float* w = (s ? Wd : Ws) + ((size_t)r*KK + k)*HD + h*DD;
    const float* a = (s ? ar : al) + (size_t)(r*HH + h)*DD;
    float acc = 0.f;
    #pragma unroll 8
    for (int d=0; d<DD; ++d) acc += w[d]*a[d];
    wcat[(k<<4) + j] = acc;
}

// eall[n][j] = x[n,:] @ wcat[:,j]   ([N,16])  — stays f32 for attention precision
__global__ __launch_bounds__(256) void k_eall(const float* __restrict__ x,
                                              const float* __restrict__ wcat,
                                              float* __restrict__ eall){
    int gid = blockIdx.x*blockDim.x + threadIdx.x;
    if (gid >= NN*16) return;
    int n = gid >> 4, j = gid & 15;
    const float* xr = x + (size_t)n*KK;
    float acc = 0.f;
    for (int k = 0; k < KK; k += 4){
        float4 xv = *(const float4*)(xr + k);
        acc += xv.x*wcat[(k+0)*16+j] + xv.y*wcat[(k+1)*16+j]
             + xv.z*wcat[(k+2)*16+j] + xv.w*wcat[(k+3)*16+j];
    }
    eall[gid] = acc;
}

// Wt[r][n][k] = bf16(W_src[r][k][n])  — transposed so GEMM B-staging is row-contiguous
__global__ void k_castW(const float* __restrict__ W, ushort* __restrict__ Wt){
    int gid = blockIdx.x*blockDim.x + threadIdx.x;
    if (gid >= RR*KK*HD) return;
    int r = gid >> 16;
    int idx = gid & 65535;
    int n = idx >> 8, k = idx & 255;
    Wt[gid] = f2bf(W[((size_t)r*KK + k)*HD + n]);
}

__global__ void k_setup(unsigned* __restrict__ cnt, unsigned* __restrict__ cur,
                        unsigned* __restrict__ cursor){
    int gid = blockIdx.x*blockDim.x + threadIdx.x;
    if (gid < RR*NN){ cnt[gid] = 0u; cur[gid] = 0u; }
    if (gid == 0) *cursor = 0u;
}

__global__ void k_hist(const int* __restrict__ didx, unsigned* __restrict__ cnt){
    int gid = blockIdx.x*blockDim.x + threadIdx.x;
    if (gid >= RR*EE) return;
    int r = gid / EE;
    atomicAdd(&cnt[(size_t)r*NN + didx[gid]], 1u);
}

// segment base allocation: wave-scan + one cursor atomic per wave (order-free CSR)
__global__ void k_alloc(const unsigned* __restrict__ cnt, unsigned* __restrict__ base,
                        unsigned* __restrict__ cursor){
    int gid = blockIdx.x*blockDim.x + threadIdx.x;
    int lane = threadIdx.x & 63;
    unsigned c = (gid < RR*NN) ? cnt[gid] : 0u;
    unsigned x = c;
    #pragma unroll
    for (int off = 1; off < 64; off <<= 1){
        unsigned t = __shfl_up(x, off, 64);
        if (lane >= off) x += t;
    }
    unsigned wtotal = __shfl(x, 63, 64);
    unsigned wbase = 0u;
    if (lane == 63) wbase = atomicAdd(cursor, wtotal);
    wbase = __shfl(wbase, 63, 64);
    if (gid < RR*NN) base[gid] = wbase + x - c;
}

__global__ void k_scatter(const int* __restrict__ sidx, const int* __restrict__ didx,
                          const unsigned* __restrict__ base, unsigned* __restrict__ cur,
                          int* __restrict__ esrc){
    int gid = blockIdx.x*blockDim.x + threadIdx.x;
    if (gid >= RR*EE) return;
    int r = gid / EE;
    size_t rn = (size_t)r*NN + didx[gid];
    unsigned pos = base[rn] + atomicAdd(&cur[rn], 1u);
    esrc[pos] = sidx[gid];
}

// bf16 MFMA GEMM: C[M,256] = A[M,256] @ W[256,256], A f32 reg-staged -> bf16,
// B from pre-transposed bf16 Wt via global_load_lds. LDS XOR-swizzled (T2).
__global__ __launch_bounds__(256) void k_gemm(const float* __restrict__ Ax,
                                              const ushort* __restrict__ Bt,
                                              float* __restrict__ C, int M){
    __shared__ ushort Ab[128*64];
    __shared__ ushort Bb[128*64];
    int tid = threadIdx.x;
    int w = tid >> 6, lane = tid & 63;
    int m0 = blockIdx.x * 128;
    int n0 = blockIdx.y * 128;
    int wm = w >> 1, wn = w & 1;      // 2x2 wave grid, 64x64 per wave
    f32x4 acc[4][4] = {};
    int srow  = lane >> 3;                    // row within 8-row chunk
    int sunit = (lane & 7) ^ srow;            // pre-swizzled global 16B unit

    for (int k0 = 0; k0 < KK; k0 += 64){
        // stage A: f32 -> bf16, swizzled ds_write_b64 (2048 float4s / block)
        #pragma unroll
        for (int i = 0; i < 8; ++i){
            int flat = tid + 256*i;           // 0..2047
            int row  = flat >> 4;             // 0..127
            int q    = flat & 15;             // float4 index within row
            int ar = m0 + row; if (ar >= M) ar = M-1;
            float4 v = *(const float4*)(Ax + (size_t)ar*KK + k0 + q*4);
            ushort4 b;
            b.x = f2bf(v.x); b.y = f2bf(v.y); b.z = f2bf(v.z); b.w = f2bf(v.w);
            int usw = (q >> 1) ^ (row & 7);
            *(ushort4*)((char*)Ab + row*128 + usw*16 + (q & 1)*8) = b;
        }
        // stage B: global_load_lds 16B, source pre-swizzled (both-sides rule)
        #pragma unroll
        for (int i = 0; i < 4; ++i){
            int row = i*32 + w*8 + srow;      // n-index 0..127
            const ushort* gb = Bt + (size_t)(n0 + row)*KK + k0 + sunit*8;
            __builtin_amdgcn_global_load_lds(
                (const __attribute__((address_space(1))) void*)gb,
                (__attribute__((address_space(3))) void*)(Bb + (i*32 + w*8)*64),
                16, 0, 0);
        }
        __syncthreads();
        #pragma unroll
        for (int kk = 0; kk < 64; kk += 32){
            bfx8 af[4], bfr[4];
            int r16 = lane & 15;
            int ublk = (lane >> 4) + (kk >> 3);   // logical 16B unit 0..7
            #pragma unroll
            for (int m = 0; m < 4; ++m){
                int row = wm*64 + m*16 + r16;
                af[m] = *(const bfx8*)(Ab + row*64 + ((ublk ^ (row & 7)) << 3));
            }
            #pragma unroll
            for (int n = 0; n < 4; ++n){
                int col = wn*64 + n*16 + r16;
                bfr[n] = *(const bfx8*)(Bb + col*64 + ((ublk ^ (col & 7)) << 3));
            }
            #pragma unroll
            for (int m = 0; m < 4; ++m)
                #pragma unroll
                for (int n = 0; n < 4; ++n)
                    acc[m][n] = __builtin_amdgcn_mfma_f32_16x16x32_bf16(
                                    af[m], bfr[n], acc[m][n], 0, 0, 0);
        }
        __syncthreads();
    }
    // epilogue: C/D layout col=lane&15, row=(lane>>4)*4+i
    int cr = lane >> 4, cc = lane & 15;
    #pragma unroll
    for (int m = 0; m < 4; ++m){
        #pragma unroll
        for (int i = 0; i < 4; ++i){
            int row = m0 + wm*64 + m*16 + cr*4 + i;
            if (row < M){
                #pragma unroll
                for (int n = 0; n < 4; ++n)
                    C[(size_t)row*HD + n0 + wn*64 + n*16 + cc] = acc[m][n][i];
            }
        }
    }
}

// one wave per dst node: single-pass online softmax + weighted gather. No atomics.
template<int FIRST>
__global__ __launch_bounds__(256) void k_agg(const unsigned* __restrict__ base,
                                             const unsigned* __restrict__ cnt,
                                             const int* __restrict__ esrc,
                                             const float* __restrict__ eall, int roff,
                                             const float* __restrict__ fs,
                                             const float* __restrict__ bias,
                                             float* __restrict__ out){
    int n = blockIdx.x*4 + (threadIdx.x >> 6);
    int lane = threadIdx.x & 63;
    int h = lane >> 4;
    unsigned beg = base[n], num = cnt[n];
    float er = eall[(size_t)n*16 + roff + 4 + h];
    float m = -1e30f, den = 0.f;
    float ax = 0.f, ay = 0.f, az = 0.f, aw = 0.f;
    for (unsigned u = beg; u < beg + num; ++u){
        int s = esrc[u];
        float v = eall[(size_t)s*16 + roff + h] + er;
        v = v > 0.f ? v : NEG_SLOPE*v;
        float mn = fmaxf(m, v);
        float sc = __expf(m - mn);
        float p  = __expf(v - mn);
        m = mn;
        den = den*sc + p;
        float4 f = *(const float4*)(fs + (size_t)s*HD + lane*4);
        ax = ax*sc + p*f.x; ay = ay*sc + p*f.y;
        az = az*sc + p*f.z; aw = aw*sc + p*f.w;
    }
    float inv = den > 0.f ? 1.f/den : 0.f;
    ax *= inv; ay *= inv; az *= inv; aw *= inv;
    float* o = out + (size_t)n*HD + lane*4;
    if (FIRST){
        const float4 b0 = *(const float4*)(bias + lane*4);
        const float4 b1 = *(const float4*)(bias + HD + lane*4);
        *(float4*)o = make_float4(ax + b0.x + b1.x, ay + b0.y + b1.y,
                                  az + b0.z + b1.z, aw + b0.w + b1.w);
    } else {
        float4 p4 = *(float4*)o;
        *(float4*)o = make_float4(ax + p4.x, ay + p4.y, az + p4.z, aw + p4.w);
    }
}

extern "C" void kernel_launch(void* const* d_in, const int* in_sizes, int n_in,
                              void* d_out, int out_size, void* d_ws, size_t ws_size,
                              hipStream_t stream) {
    const float* x     = (const float*)d_in[0];
    const float* W_src = (const float*)d_in[1];
    const float* W_dst = (const float*)d_in[2];
    const float* al    = (const float*)d_in[3];
    const float* ar    = (const float*)d_in[4];
    const float* bias  = (const float*)d_in[5];
    const int*   sidx  = (const int*)d_in[6];
    const int*   didx  = (const int*)d_in[7];
    float* out = (float*)d_out;

    // workspace carve-up (~116 MB)
    float*    fs     = (float*)d_ws;                        // N*HD f32
    float*    eall   = fs + (size_t)NN*HD;                  // N*16 f32
    float*    wcat   = eall + (size_t)NN*16;                // 4096 f32
    ushort*   Wt     = (ushort*)(wcat + KK*16);             // R*256*256 bf16
    unsigned* cnt    = (unsigned*)(Wt + (size_t)RR*KK*HD);  // R*N
    unsigned* cur    = cnt + (size_t)RR*NN;                 // R*N
    unsigned* base   = cur + (size_t)RR*NN;                 // R*N
    unsigned* cursor = base + (size_t)RR*NN;                // 1 (+7 pad)
    int*      esrc   = (int*)(cursor + 8);                  // R*E

    k_wcat<<<(KK*16 + 255)/256, 256, 0, stream>>>(W_src, W_dst, al, ar, wcat);
    k_eall<<<(NN*16 + 255)/256, 256, 0, stream>>>(x, wcat, eall);
    k_castW<<<(RR*KK*HD + 255)/256, 256, 0, stream>>>(W_src, Wt);
    k_setup<<<(RR*NN + 255)/256, 256, 0, stream>>>(cnt, cur, cursor);
    k_hist<<<(RR*EE + 255)/256, 256, 0, stream>>>(didx, cnt);
    k_alloc<<<(RR*NN + 255)/256, 256, 0, stream>>>(cnt, base, cursor);
    k_scatter<<<(RR*EE + 255)/256, 256, 0, stream>>>(sidx, didx, base, cur, esrc);

    for (int r = 0; r < RR; ++r){
        k_gemm<<<dim3((NN + 127)/128, 2), 256, 0, stream>>>(x, Wt + (size_t)r*KK*HD, fs, NN);
        const unsigned* br = base + (size_t)r*NN;
        const unsigned* cr = cnt + (size_t)r*NN;
        if (r == 0)
            k_agg<1><<<NN/4, 256, 0, stream>>>(br, cr, esrc, eall, r*8, fs, bias, out);
        else
            k_agg<0><<<NN/4, 256, 0, stream>>>(br, cr, esrc, eall, r*8, fs, bias, out);
    }
}

// Round 4
// 401.925 us; speedup vs baseline: 9.7643x; 1.3939x over previous
//
#include <hip/hip_runtime.h>
#include <hip/hip_bf16.h>

#define NN 100000   // nodes
#define NNP 100032  // NN padded to 64
#define HH 4        // heads
#define DD 64       // dim per head
#define RR 2        // relations
#define EE 500000   // edges per relation
#define KK 256      // in_feat
#define HD 256      // H*D
#define NEG_SLOPE 0.2f

typedef __attribute__((ext_vector_type(8))) short bfx8;
typedef __attribute__((ext_vector_type(4))) float f32x4;

__device__ __forceinline__ ushort f2bf(float f){
    __hip_bfloat16 h = __float2bfloat16(f);
    return *(ushort*)&h;
}
__device__ __forceinline__ float bf2f(ushort u){
    return __uint_as_float(((unsigned)u) << 16);
}
__device__ __forceinline__ bfx8 cvt8(float4 v0, float4 v1){
    bfx8 a;
    a[0]=(short)f2bf(v0.x); a[1]=(short)f2bf(v0.y);
    a[2]=(short)f2bf(v0.z); a[3]=(short)f2bf(v0.w);
    a[4]=(short)f2bf(v1.x); a[5]=(short)f2bf(v1.y);
    a[6]=(short)f2bf(v1.z); a[7]=(short)f2bf(v1.w);
    return a;
}

// wcatbT[j][k] = bf16( sum_d W[k][h*64+d]*attn[h][d] ), j = r*8 + s*4 + h
__global__ void k_wcat(const float* __restrict__ Ws, const float* __restrict__ Wd,
                       const float* __restrict__ al, const float* __restrict__ ar,
                       ushort* __restrict__ wcatbT){
    int gid = blockIdx.x*blockDim.x + threadIdx.x;
    if (gid >= KK*16) return;
    int k = gid >> 4, j = gid & 15;
    int r = j >> 3, s = (j >> 2) & 1, h = j & 3;
    const float* w = (s ? Wd : Ws) + ((size_t)r*KK + k)*HD + h*DD;
    const float* a = (s ? ar : al) + (size_t)(r*HH + h)*DD;
    float acc = 0.f;
    #pragma unroll 8
    for (int d=0; d<DD; ++d) acc += w[d]*a[d];
    wcatbT[(size_t)j*KK + k] = f2bf(acc);
}

// Wt[r][n][k] = bf16(W_src[r][k][n])  — transposed for GEMM B-staging
__global__ void k_castW(const float* __restrict__ W, ushort* __restrict__ Wt){
    int gid = blockIdx.x*blockDim.x + threadIdx.x;
    if (gid >= RR*KK*HD) return;
    int r = gid >> 16;
    int idx = gid & 65535;
    int n = idx >> 8, k = idx & 255;
    Wt[gid] = f2bf(W[((size_t)r*KK + k)*HD + n]);
}

// Fused: eall = bf16MFMA(x @ wcat) [N,16]  AND  xb = bf16(x) side-product.
// One wave per 16 rows. A-frags straight from global f32 x (cvt in reg).
__global__ __launch_bounds__(256) void k_eall(const float* __restrict__ x,
                                              const ushort* __restrict__ wcatbT,
                                              float* __restrict__ eall,
                                              ushort* __restrict__ xb){
    int w = threadIdx.x >> 6, lane = threadIdx.x & 63;
    int n0 = blockIdx.x*64 + w*16;
    int r16 = lane & 15, ksub = lane >> 4;
    int row = n0 + r16;
    int rowc = row < NN ? row : NN-1;
    const float* xr = x + (size_t)rowc*KK;
    f32x4 acc = {};
    #pragma unroll
    for (int kk = 0; kk < 8; ++kk){
        int kb = ksub*8 + kk*32;
        float4 v0 = *(const float4*)(xr + kb);
        float4 v1 = *(const float4*)(xr + kb + 4);
        bfx8 a = cvt8(v0, v1);
        *(bfx8*)(xb + (size_t)row*KK + kb) = a;   // padded buffer, row<NNP always
        bfx8 b = *(const bfx8*)(wcatbT + (size_t)r16*KK + kb);
        acc = __builtin_amdgcn_mfma_f32_16x16x32_bf16(a, b, acc, 0, 0, 0);
    }
    #pragma unroll
    for (int i = 0; i < 4; ++i){
        int nr = n0 + ksub*4 + i;
        if (nr < NN) eall[(size_t)nr*16 + r16] = acc[i];
    }
}

__global__ void k_setup(unsigned* __restrict__ cnt, unsigned* __restrict__ cur,
                        unsigned* __restrict__ cursor){
    int gid = blockIdx.x*blockDim.x + threadIdx.x;
    if (gid < RR*NN){ cnt[gid] = 0u; cur[gid] = 0u; }
    if (gid == 0) *cursor = 0u;
}

__global__ void k_hist(const int* __restrict__ didx, unsigned* __restrict__ cnt){
    int gid = blockIdx.x*blockDim.x + threadIdx.x;
    if (gid >= RR*EE) return;
    int r = gid / EE;
    atomicAdd(&cnt[(size_t)r*NN + didx[gid]], 1u);
}

// segment base allocation: wave-scan + one cursor atomic per wave (order-free CSR)
__global__ void k_alloc(const unsigned* __restrict__ cnt, unsigned* __restrict__ base,
                        unsigned* __restrict__ cursor){
    int gid = blockIdx.x*blockDim.x + threadIdx.x;
    int lane = threadIdx.x & 63;
    unsigned c = (gid < RR*NN) ? cnt[gid] : 0u;
    unsigned x = c;
    #pragma unroll
    for (int off = 1; off < 64; off <<= 1){
        unsigned t = __shfl_up(x, off, 64);
        if (lane >= off) x += t;
    }
    unsigned wtotal = __shfl(x, 63, 64);
    unsigned wbase = 0u;
    if (lane == 63) wbase = atomicAdd(cursor, wtotal);
    wbase = __shfl(wbase, 63, 64);
    if (gid < RR*NN) base[gid] = wbase + x - c;
}

__global__ void k_scatter(const int* __restrict__ sidx, const int* __restrict__ didx,
                          const unsigned* __restrict__ base, unsigned* __restrict__ cur,
                          int* __restrict__ esrc){
    int gid = blockIdx.x*blockDim.x + threadIdx.x;
    if (gid >= RR*EE) return;
    int r = gid / EE;
    size_t rn = (size_t)r*NN + didx[gid];
    unsigned pos = base[rn] + atomicAdd(&cur[rn], 1u);
    esrc[pos] = sidx[gid];
}

// bf16 MFMA GEMM: C_bf16[M,256] = xb[M,256] @ W[256,256].
// A and B both via global_load_lds (16B) with pre-swizzled sources (T2 both-sides).
__global__ __launch_bounds__(256) void k_gemm(const ushort* __restrict__ Axb,
                                              const ushort* __restrict__ Bt,
                                              ushort* __restrict__ C, int M){
    __shared__ ushort Ab[128*64];
    __shared__ ushort Bb[128*64];
    int tid = threadIdx.x;
    int w = tid >> 6, lane = tid & 63;
    int m0 = blockIdx.x * 128;
    int n0 = blockIdx.y * 128;
    int wm = w >> 1, wn = w & 1;      // 2x2 wave grid, 64x64 per wave
    f32x4 acc[4][4] = {};
    int srow  = lane >> 3;            // row within 8-row chunk
    int sunit = (lane & 7) ^ srow;    // pre-swizzled source 16B unit

    for (int k0 = 0; k0 < KK; k0 += 64){
        #pragma unroll
        for (int i = 0; i < 4; ++i){
            int rowl = i*32 + w*8 + srow;
            int arow = m0 + rowl; if (arow >= M) arow = M-1;
            const ushort* ga = Axb + (size_t)arow*KK + k0 + sunit*8;
            __builtin_amdgcn_global_load_lds(
                (const __attribute__((address_space(1))) void*)ga,
                (__attribute__((address_space(3))) void*)(Ab + (i*32 + w*8)*64),
                16, 0, 0);
            const ushort* gb = Bt + (size_t)(n0 + rowl)*KK + k0 + sunit*8;
            __builtin_amdgcn_global_load_lds(
                (const __attribute__((address_space(1))) void*)gb,
                (__attribute__((address_space(3))) void*)(Bb + (i*32 + w*8)*64),
                16, 0, 0);
        }
        __syncthreads();
        #pragma unroll
        for (int kk = 0; kk < 64; kk += 32){
            bfx8 af[4], bfr[4];
            int r16 = lane & 15;
            int ublk = (lane >> 4) + (kk >> 3);   // logical 16B unit 0..7
            #pragma unroll
            for (int m = 0; m < 4; ++m){
                int row = wm*64 + m*16 + r16;
                af[m] = *(const bfx8*)(Ab + row*64 + ((ublk ^ (row & 7)) << 3));
            }
            #pragma unroll
            for (int n = 0; n < 4; ++n){
                int col = wn*64 + n*16 + r16;
                bfr[n] = *(const bfx8*)(Bb + col*64 + ((ublk ^ (col & 7)) << 3));
            }
            #pragma unroll
            for (int m = 0; m < 4; ++m)
                #pragma unroll
                for (int n = 0; n < 4; ++n)
                    acc[m][n] = __builtin_amdgcn_mfma_f32_16x16x32_bf16(
                                    af[m], bfr[n], acc[m][n], 0, 0, 0);
        }
        __syncthreads();
    }
    // epilogue: C/D layout col=lane&15, row=(lane>>4)*4+i ; store bf16
    int cr = lane >> 4, cc = lane & 15;
    #pragma unroll
    for (int m = 0; m < 4; ++m){
        #pragma unroll
        for (int i = 0; i < 4; ++i){
            int row = m0 + wm*64 + m*16 + cr*4 + i;
            if (row < M){
                #pragma unroll
                for (int n = 0; n < 4; ++n)
                    C[(size_t)row*HD + n0 + wn*64 + n*16 + cc] = f2bf(acc[m][n][i]);
            }
        }
    }
}

// one wave per dst node: single-pass online softmax + weighted gather (bf16 fs)
template<int FIRST>
__global__ __launch_bounds__(256) void k_agg(const unsigned* __restrict__ base,
                                             const unsigned* __restrict__ cnt,
                                             const int* __restrict__ esrc,
                                             const float* __restrict__ eall, int roff,
                                             const ushort* __restrict__ fsb,
                                             const float* __restrict__ bias,
                                             float* __restrict__ out){
    int n = blockIdx.x*4 + (threadIdx.x >> 6);
    int lane = threadIdx.x & 63;
    int h = lane >> 4;
    unsigned beg = base[n], num = cnt[n];
    float er = eall[(size_t)n*16 + roff + 4 + h];
    float m = -1e30f, den = 0.f;
    float ax = 0.f, ay = 0.f, az = 0.f, aw = 0.f;
    for (unsigned u = beg; u < beg + num; ++u){
        int s = esrc[u];
        float v = eall[(size_t)s*16 + roff + h] + er;
        v = v > 0.f ? v : NEG_SLOPE*v;
        float mn = fmaxf(m, v);
        float sc = __expf(m - mn);
        float p  = __expf(v - mn);
        m = mn;
        den = den*sc + p;
        ushort4 f = *(const ushort4*)(fsb + (size_t)s*HD + lane*4);
        ax = ax*sc + p*bf2f(f.x); ay = ay*sc + p*bf2f(f.y);
        az = az*sc + p*bf2f(f.z); aw = aw*sc + p*bf2f(f.w);
    }
    float inv = den > 0.f ? 1.f/den : 0.f;
    ax *= inv; ay *= inv; az *= inv; aw *= inv;
    float* o = out + (size_t)n*HD + lane*4;
    if (FIRST){
        const float4 b0 = *(const float4*)(bias + lane*4);
        const float4 b1 = *(const float4*)(bias + HD + lane*4);
        *(float4*)o = make_float4(ax + b0.x + b1.x, ay + b0.y + b1.y,
                                  az + b0.z + b1.z, aw + b0.w + b1.w);
    } else {
        float4 p4 = *(float4*)o;
        *(float4*)o = make_float4(ax + p4.x, ay + p4.y, az + p4.z, aw + p4.w);
    }
}

extern "C" void kernel_launch(void* const* d_in, const int* in_sizes, int n_in,
                              void* d_out, int out_size, void* d_ws, size_t ws_size,
                              hipStream_t stream) {
    const float* x     = (const float*)d_in[0];
    const float* W_src = (const float*)d_in[1];
    const float* W_dst = (const float*)d_in[2];
    const float* al    = (const float*)d_in[3];
    const float* ar    = (const float*)d_in[4];
    const float* bias  = (const float*)d_in[5];
    const int*   sidx  = (const int*)d_in[6];
    const int*   didx  = (const int*)d_in[7];
    float* out = (float*)d_out;

    // workspace carve-up (~116 MB)
    ushort*   fsb    = (ushort*)d_ws;                        // NN*HD bf16
    ushort*   xb     = fsb + (size_t)NN*HD;                  // NNP*KK bf16
    ushort*   Wt     = xb + (size_t)NNP*KK;                  // R*256*256 bf16
    ushort*   wcatbT = Wt + (size_t)RR*KK*HD;                // 16*256 bf16
    float*    eall   = (float*)(wcatbT + 16*KK);             // N*16 f32
    unsigned* cnt    = (unsigned*)(eall + (size_t)NN*16);    // R*N
    unsigned* cur    = cnt + (size_t)RR*NN;                  // R*N
    unsigned* base   = cur + (size_t)RR*NN;                  // R*N
    unsigned* cursor = base + (size_t)RR*NN;                 // 1 (+7 pad)
    int*      esrc   = (int*)(cursor + 8);                   // R*E

    k_wcat<<<(KK*16 + 255)/256, 256, 0, stream>>>(W_src, W_dst, al, ar, wcatbT);
    k_castW<<<(RR*KK*HD + 255)/256, 256, 0, stream>>>(W_src, Wt);
    k_eall<<<(NNP + 63)/64, 256, 0, stream>>>(x, wcatbT, eall, xb);
    k_setup<<<(RR*NN + 255)/256, 256, 0, stream>>>(cnt, cur, cursor);
    k_hist<<<(RR*EE + 255)/256, 256, 0, stream>>>(didx, cnt);
    k_alloc<<<(RR*NN + 255)/256, 256, 0, stream>>>(cnt, base, cursor);
    k_scatter<<<(RR*EE + 255)/256, 256, 0, stream>>>(sidx, didx, base, cur, esrc);

    for (int r = 0; r < RR; ++r){
        k_gemm<<<dim3((NN + 127)/128, 2), 256, 0, stream>>>(xb, Wt + (size_t)r*KK*HD, fsb, NN);
        const unsigned* br = base + (size_t)r*NN;
        const unsigned* cr = cnt + (size_t)r*NN;
        if (r == 0)
            k_agg<1><<<NN/4, 256, 0, stream>>>(br, cr, esrc, eall, r*8, fsb, bias, out);
        else
            k_agg<0><<<NN/4, 256, 0, stream>>>(br, cr, esrc, eall, r*8, fsb, bias, out);
    }
}

// Round 5
// 377.571 us; speedup vs baseline: 10.3942x; 1.0645x over previous
//
#include <hip/hip_runtime.h>
#include <hip/hip_bf16.h>

#define NN 100000   // nodes
#define NNP 100032  // NN padded to 64
#define HH 4        // heads
#define DD 64       // dim per head
#define RR 2        // relations
#define EE 500000   // edges per relation
#define KK 256      // in_feat
#define HD 256      // H*D
#define HD2 512     // both relations' features per node
#define NEG_SLOPE 0.2f

typedef __attribute__((ext_vector_type(8))) short bfx8;
typedef __attribute__((ext_vector_type(4))) float f32x4;

__device__ __forceinline__ ushort f2bf(float f){
    __hip_bfloat16 h = __float2bfloat16(f);
    return *(ushort*)&h;
}
__device__ __forceinline__ float bf2f(ushort u){
    return __uint_as_float(((unsigned)u) << 16);
}
__device__ __forceinline__ bfx8 cvt8(float4 v0, float4 v1){
    bfx8 a;
    a[0]=(short)f2bf(v0.x); a[1]=(short)f2bf(v0.y);
    a[2]=(short)f2bf(v0.z); a[3]=(short)f2bf(v0.w);
    a[4]=(short)f2bf(v1.x); a[5]=(short)f2bf(v1.y);
    a[6]=(short)f2bf(v1.z); a[7]=(short)f2bf(v1.w);
    return a;
}

// wcatbT[j][k] = bf16( sum_d W[k][h*64+d]*attn[h][d] ), j = r*8 + s*4 + h
__global__ void k_wcat(const float* __restrict__ Ws, const float* __restrict__ Wd,
                       const float* __restrict__ al, const float* __restrict__ ar,
                       ushort* __restrict__ wcatbT){
    int gid = blockIdx.x*blockDim.x + threadIdx.x;
    if (gid >= KK*16) return;
    int k = gid >> 4, j = gid & 15;
    int r = j >> 3, s = (j >> 2) & 1, h = j & 3;
    const float* w = (s ? Wd : Ws) + ((size_t)r*KK + k)*HD + h*DD;
    const float* a = (s ? ar : al) + (size_t)(r*HH + h)*DD;
    float acc = 0.f;
    #pragma unroll 8
    for (int d=0; d<DD; ++d) acc += w[d]*a[d];
    wcatbT[(size_t)j*KK + k] = f2bf(acc);
}

// Wt[r*256+n][k] = bf16(W_src[r][k][n])  — transposed, both relations stacked
__global__ void k_castW(const float* __restrict__ W, ushort* __restrict__ Wt){
    int gid = blockIdx.x*blockDim.x + threadIdx.x;
    if (gid >= RR*KK*HD) return;
    int r = gid >> 16;
    int idx = gid & 65535;
    int n = idx >> 8, k = idx & 255;
    Wt[gid] = f2bf(W[((size_t)r*KK + k)*HD + n]);
}

// eall = bf16MFMA(x @ wcat) [N,16]; one wave per 16 rows
__global__ __launch_bounds__(256) void k_eall(const float* __restrict__ x,
                                              const ushort* __restrict__ wcatbT,
                                              float* __restrict__ eall){
    int w = threadIdx.x >> 6, lane = threadIdx.x & 63;
    int n0 = blockIdx.x*64 + w*16;
    int r16 = lane & 15, ksub = lane >> 4;
    int row = n0 + r16;
    int rowc = row < NN ? row : NN-1;
    const float* xr = x + (size_t)rowc*KK;
    f32x4 acc = {};
    #pragma unroll
    for (int kk = 0; kk < 8; ++kk){
        int kb = ksub*8 + kk*32;
        float4 v0 = *(const float4*)(xr + kb);
        float4 v1 = *(const float4*)(xr + kb + 4);
        bfx8 a = cvt8(v0, v1);
        bfx8 b = *(const bfx8*)(wcatbT + (size_t)r16*KK + kb);
        acc = __builtin_amdgcn_mfma_f32_16x16x32_bf16(a, b, acc, 0, 0, 0);
    }
    #pragma unroll
    for (int i = 0; i < 4; ++i){
        int nr = n0 + ksub*4 + i;
        if (nr < NN) eall[(size_t)nr*16 + r16] = acc[i];
    }
}

__global__ void k_hist(const int* __restrict__ didx, unsigned* __restrict__ cnt){
    int gid = blockIdx.x*blockDim.x + threadIdx.x;
    if (gid >= RR*EE) return;
    int r = gid / EE;
    atomicAdd(&cnt[(size_t)r*NN + didx[gid]], 1u);
}

// segment base allocation: wave-scan + one cursor atomic per wave (order-free CSR)
__global__ void k_alloc(const unsigned* __restrict__ cnt, unsigned* __restrict__ base,
                        unsigned* __restrict__ cursor){
    int gid = blockIdx.x*blockDim.x + threadIdx.x;
    int lane = threadIdx.x & 63;
    unsigned c = (gid < RR*NN) ? cnt[gid] : 0u;
    unsigned x = c;
    #pragma unroll
    for (int off = 1; off < 64; off <<= 1){
        unsigned t = __shfl_up(x, off, 64);
        if (lane >= off) x += t;
    }
    unsigned wtotal = __shfl(x, 63, 64);
    unsigned wbase = 0u;
    if (lane == 63) wbase = atomicAdd(cursor, wtotal);
    wbase = __shfl(wbase, 63, 64);
    if (gid < RR*NN) base[gid] = wbase + x - c;
}

__global__ void k_scatter(const int* __restrict__ sidx, const int* __restrict__ didx,
                          const unsigned* __restrict__ base, unsigned* __restrict__ cur,
                          int* __restrict__ esrc){
    int gid = blockIdx.x*blockDim.x + threadIdx.x;
    if (gid >= RR*EE) return;
    int r = gid / EE;
    size_t rn = (size_t)r*NN + didx[gid];
    unsigned pos = base[rn] + atomicAdd(&cur[rn], 1u);
    esrc[pos] = sidx[gid];
}

// bf16 MFMA GEMM: fsall[M,512] = x[M,256] @ Wt^T (both relations).
// A: f32 reg-staged -> bf16, swizzled ds_write. B: global_load_lds, pre-swizzled src.
__global__ __launch_bounds__(256) void k_gemm(const float* __restrict__ Ax,
                                              const ushort* __restrict__ Bt,
                                              ushort* __restrict__ C){
    __shared__ ushort Ab[128*64];
    __shared__ ushort Bb[128*64];
    int tid = threadIdx.x;
    int w = tid >> 6, lane = tid & 63;
    int m0 = blockIdx.x * 128;
    int n0 = blockIdx.y * 128;
    int wm = w >> 1, wn = w & 1;      // 2x2 wave grid, 64x64 per wave
    f32x4 acc[4][4] = {};
    int srow  = lane >> 3;            // row within 8-row chunk
    int sunit = (lane & 7) ^ srow;    // pre-swizzled source 16B unit

    for (int k0 = 0; k0 < KK; k0 += 64){
        // stage A: f32 -> bf16, swizzled ds_write_b64
        #pragma unroll
        for (int i = 0; i < 8; ++i){
            int flat = tid + 256*i;           // 0..2047
            int row  = flat >> 4;             // 0..127
            int q    = flat & 15;             // float4 index within row
            int arw = m0 + row; if (arw >= NN) arw = NN-1;
            float4 v = *(const float4*)(Ax + (size_t)arw*KK + k0 + q*4);
            ushort4 b;
            b.x = f2bf(v.x); b.y = f2bf(v.y); b.z = f2bf(v.z); b.w = f2bf(v.w);
            int usw = (q >> 1) ^ (row & 7);
            *(ushort4*)((char*)Ab + row*128 + usw*16 + (q & 1)*8) = b;
        }
        // stage B: global_load_lds 16B, source pre-swizzled (both-sides rule)
        #pragma unroll
        for (int i = 0; i < 4; ++i){
            int rowl = i*32 + w*8 + srow;     // n-index 0..127
            const ushort* gb = Bt + (size_t)(n0 + rowl)*KK + k0 + sunit*8;
            __builtin_amdgcn_global_load_lds(
                (const __attribute__((address_space(1))) void*)gb,
                (__attribute__((address_space(3))) void*)(Bb + rowl*64 - srow*64 + srow*64),
                16, 0, 0);
        }
        __syncthreads();
        #pragma unroll
        for (int kk = 0; kk < 64; kk += 32){
            bfx8 af[4], bfr[4];
            int r16 = lane & 15;
            int ublk = (lane >> 4) + (kk >> 3);   // logical 16B unit 0..7
            #pragma unroll
            for (int m = 0; m < 4; ++m){
                int row = wm*64 + m*16 + r16;
                af[m] = *(const bfx8*)(Ab + row*64 + ((ublk ^ (row & 7)) << 3));
            }
            #pragma unroll
            for (int n = 0; n < 4; ++n){
                int col = wn*64 + n*16 + r16;
                bfr[n] = *(const bfx8*)(Bb + col*64 + ((ublk ^ (col & 7)) << 3));
            }
            #pragma unroll
            for (int m = 0; m < 4; ++m)
                #pragma unroll
                for (int n = 0; n < 4; ++n)
                    acc[m][n] = __builtin_amdgcn_mfma_f32_16x16x32_bf16(
                                    af[m], bfr[n], acc[m][n], 0, 0, 0);
        }
        __syncthreads();
    }
    // epilogue: C/D layout col=lane&15, row=(lane>>4)*4+i ; store bf16, stride 512
    int cr = lane >> 4, cc = lane & 15;
    #pragma unroll
    for (int m = 0; m < 4; ++m){
        #pragma unroll
        for (int i = 0; i < 4; ++i){
            int row = m0 + wm*64 + m*16 + cr*4 + i;
            #pragma unroll
            for (int n = 0; n < 4; ++n)
                C[(size_t)row*HD2 + n0 + wn*64 + n*16 + cc] = f2bf(acc[m][n][i]);
        }
    }
}

// one wave per dst node, BOTH relations: online softmax + gather, single out write.
__global__ __launch_bounds__(256) void k_agg(const unsigned* __restrict__ base,
                                             const unsigned* __restrict__ cnt,
                                             const int* __restrict__ esrc,
                                             const float* __restrict__ eall,
                                             const ushort* __restrict__ fsall,
                                             const float* __restrict__ bias,
                                             float* __restrict__ out){
    int n = blockIdx.x*4 + (threadIdx.x >> 6);
    int lane = threadIdx.x & 63;
    int h = lane >> 4;
    float rx = 0.f, ry = 0.f, rz = 0.f, rw = 0.f;
    #pragma unroll
    for (int r = 0; r < RR; ++r){
        unsigned beg = base[(size_t)r*NN + n], num = cnt[(size_t)r*NN + n];
        float er = eall[(size_t)n*16 + r*8 + 4 + h];
        float m = -1e30f, den = 0.f;
        float ax = 0.f, ay = 0.f, az = 0.f, aw = 0.f;
        for (unsigned u = beg; u < beg + num; ++u){
            int s = esrc[u];
            float v = eall[(size_t)s*16 + r*8 + h] + er;
            v = v > 0.f ? v : NEG_SLOPE*v;
            float mn = fmaxf(m, v);
            float sc = __expf(m - mn);
            float p  = __expf(v - mn);
            m = mn;
            den = den*sc + p;
            ushort4 f = *(const ushort4*)(fsall + (size_t)s*HD2 + r*HD + lane*4);
            ax = ax*sc + p*bf2f(f.x); ay = ay*sc + p*bf2f(f.y);
            az = az*sc + p*bf2f(f.z); aw = aw*sc + p*bf2f(f.w);
        }
        float inv = den > 0.f ? 1.f/den : 0.f;
        rx += ax*inv; ry += ay*inv; rz += az*inv; rw += aw*inv;
    }
    const float4 b0 = *(const float4*)(bias + lane*4);
    const float4 b1 = *(const float4*)(bias + HD + lane*4);
    *(float4*)(out + (size_t)n*HD + lane*4) =
        make_float4(rx + b0.x + b1.x, ry + b0.y + b1.y,
                    rz + b0.z + b1.z, rw + b0.w + b1.w);
}

extern "C" void kernel_launch(void* const* d_in, const int* in_sizes, int n_in,
                              void* d_out, int out_size, void* d_ws, size_t ws_size,
                              hipStream_t stream) {
    const float* x     = (const float*)d_in[0];
    const float* W_src = (const float*)d_in[1];
    const float* W_dst = (const float*)d_in[2];
    const float* al    = (const float*)d_in[3];
    const float* ar    = (const float*)d_in[4];
    const float* bias  = (const float*)d_in[5];
    const int*   sidx  = (const int*)d_in[6];
    const int*   didx  = (const int*)d_in[7];
    float* out = (float*)d_out;

    // workspace carve-up (~116 MB)
    ushort*   fsall  = (ushort*)d_ws;                        // NNP*512 bf16
    ushort*   Wt     = fsall + (size_t)NNP*HD2;              // 512*256 bf16
    ushort*   wcatbT = Wt + (size_t)RR*KK*HD;                // 16*256 bf16
    float*    eall   = (float*)(wcatbT + 16*KK);             // N*16 f32
    unsigned* cnt    = (unsigned*)(eall + (size_t)NN*16);    // R*N
    unsigned* cur    = cnt + (size_t)RR*NN;                  // R*N
    unsigned* cursor = cur + (size_t)RR*NN;                  // 8 (1 + pad)
    unsigned* base   = cursor + 8;                           // R*N
    int*      esrc   = (int*)(base + (size_t)RR*NN);         // R*E

    k_wcat<<<(KK*16 + 255)/256, 256, 0, stream>>>(W_src, W_dst, al, ar, wcatbT);
    k_castW<<<(RR*KK*HD + 255)/256, 256, 0, stream>>>(W_src, Wt);
    k_eall<<<(NNP + 63)/64, 256, 0, stream>>>(x, wcatbT, eall);
    hipMemsetAsync(cnt, 0, (size_t)(2*RR*NN + 8)*4, stream);   // cnt, cur, cursor
    k_hist<<<(RR*EE + 255)/256, 256, 0, stream>>>(didx, cnt);
    k_alloc<<<(RR*NN + 255)/256, 256, 0, stream>>>(cnt, base, cursor);
    k_scatter<<<(RR*EE + 255)/256, 256, 0, stream>>>(sidx, didx, base, cur, esrc);

    k_gemm<<<dim3((NNP + 127)/128, HD2/128), 256, 0, stream>>>(x, Wt, fsall);
    k_agg<<<NN/4, 256, 0, stream>>>(base, cnt, esrc, eall, fsall, bias, out);
}